// Round 5
// baseline (755.106 us; speedup 1.0000x reference)
//
#include <hip/hip_runtime.h>
#include <hip/hip_bf16.h>
#include <cstdio>

typedef __bf16 bf16;
typedef __bf16 bf16x4 __attribute__((ext_vector_type(4)));
typedef __bf16 bf16x8 __attribute__((ext_vector_type(8)));
typedef float  f32x4  __attribute__((ext_vector_type(4)));

#define AS1 __attribute__((address_space(1)))
#define AS3 __attribute__((address_space(3)))

__device__ __forceinline__ void async16(void* lds, const void* g) {
    __builtin_amdgcn_global_load_lds((AS1 unsigned int*)g, (AS3 unsigned int*)lds, 16, 0, 0);
}

enum { EPI_NONE = 0, EPI_SINUS = 1, EPI_BIAS = 2, EPI_ATTN = 3 };

#define FENCE asm volatile("" ::: "memory")
#define BAR   do { FENCE; __builtin_amdgcn_s_barrier(); FENCE; } while (0)
// counted lgkm fence: reads issued above cannot sink below it ("memory" clobber);
// the compiler still inserts its own per-dependency waits, so this only *schedules*.
#define LGKMC(n) asm volatile("s_waitcnt lgkmcnt(" #n ")" ::: "memory")
#define RD8(p) (*(const bf16x8*)(const void*)(p))

// 16 MFMA: quadrant rows (MB..MB+3) x cols (NB..NB+1), K=64 (2 ksubs)
#define MFMA_Q(AF, MB, BF, NB)                                                 \
    _Pragma("unroll") for (int mf = 0; mf < 4; ++mf)                           \
    _Pragma("unroll") for (int nf = 0; nf < 2; ++nf)                           \
    _Pragma("unroll") for (int s = 0; s < 2; ++s)                              \
        acc[(MB) + mf][(NB) + nf] = __builtin_amdgcn_mfma_f32_16x16x32_bf16(   \
            AF[mf][s], BF[nf][s], acc[(MB) + mf][(NB) + nf], 0, 0, 0);

__device__ __forceinline__ void onl_merge(float& mx, float& sm, float omx, float osm) {
    float nm = fmaxf(mx, omx);
    sm = sm * __expf(mx - nm) + osm * __expf(omx - nm);
    mx = nm;
}

// ---------------- 256x256 8-phase NT GEMM, software-pipelined ds_reads ----------------
// C[m][n] = sum_k A[m][k]*B[n][k], bf16 in, CT out. BM=BN=256, BK=64, 512 thr (8 waves 2Mx4N).
// LDS 128KB: A[2buf][2half][128][64] + B same; XOR-swizzle byte^=((row&7)<<4) on both sides.
// KEY CHANGE vs prior rev: each phase's ds_reads are issued ONE PHASE EARLY with counted
// lgkm fences, so LDS-read time (~2300cy/tile/CU) hides under MFMA (~2480cy/tile/CU)
// instead of serializing with it (prior structure waited lgkmcnt(0) before each cluster).
//   read groups: G1=af03+bf01 (12, issued P4(t-1) after residency barrier)
//                G2=bf23 (4, issued P1)   G3=af47 (8, issued P2)
//   fences:      P1 lgkm(4)  P2 lgkm(8)  P3 lgkm(0)  P4 none
// A(t+2) staging moved P3->P4 (after P3's barrier): fixes a latent race where the stage
// could land over A-half rows 64..127 while lagging waves still had af47 reads pending.
// vmcnt(4) once per tile at P4: tile t+1 resident, A(t+2) (4 loads) stays in flight.
template <int EPI, typename CT>
__launch_bounds__(512, 2)
__global__ void gemm8(const bf16* __restrict__ A, long sA, int lda,
                      const bf16* __restrict__ B, long sB, int ldb,
                      CT* __restrict__ C, long sC, int ldc,
                      int K, int mLimit, const float* __restrict__ bias,
                      float* __restrict__ pmx, float* __restrict__ psum,
                      int tilesM, int tilesN)
{
    __shared__ __align__(16) char smem[131072];
    char* ldsA = smem;
    char* ldsB = smem + 65536;

    const int tid  = threadIdx.x;
    const int wave = tid >> 6;
    const int lane = tid & 63;
    const int quad = lane >> 4;
    const int l16  = lane & 15;
    const int hw   = wave >> 2;        // wave's A half (M strip)
    const int wq   = wave & 3;         // wave's N strip (64 cols)
    const int hbB  = wq >> 1;          // wave's B half
    const int rrB  = (wq & 1) * 64;    // row base within B half

    // T1: bijective XCD-chunked swizzle
    const int nwg = gridDim.x;
    const int qq = nwg >> 3, rr = nwg & 7;
    const int xcd = blockIdx.x & 7, idx = blockIdx.x >> 3;
    const int wgid = (xcd < rr ? xcd * (qq + 1) : rr * (qq + 1) + (xcd - rr) * qq) + idx;

    const int tpb = tilesM * tilesN;
    const int b   = wgid / tpb;
    const int rem = wgid - b * tpb;
    const int m0  = (rem / tilesN) * 256;
    const int n0  = (rem % tilesN) * 256;

    A += (long)b * sA;
    B += (long)b * sB;

    // staging: dest (linear) od = wave*1024 + lane*16 (+ j*8192); source pre-swizzled so that
    // LDS[od] = G[od ^ ((destrow&7)<<4)]
    const int odt  = wave * 1024 + lane * 16;
    const int ol   = odt ^ (((odt >> 7) & 7) << 4);
    const int srow = ol >> 7;            // 0..63
    const int scol = (ol & 127) >> 1;    // element col, multiple of 8
    const bf16* pA = A + (long)(m0 + srow) * lda + scol;
    const bf16* pB = B + (long)(n0 + srow) * ldb + scol;

    // ds_read lane offsets: logical (row*128 + s*64 + quad*16) ^ ((row&7)<<4); row&7 == l16&7
    const int xr = (l16 & 7) << 4;
    const int lane2_0 = ((l16 * 128) + (quad * 16)) ^ xr;
    const int lane2_1 = ((l16 * 128) + 64 + (quad * 16)) ^ xr;

    auto stgA = [&](int bb, int h, int kt) {
        char* l = ldsA + bb * 32768 + h * 16384 + wave * 1024;
        const bf16* g = pA + (long)(h * 128) * lda + kt * 64;
        async16(l, g);
        async16(l + 8192, g + (long)64 * lda);
    };
    auto stgB = [&](int bb, int h, int kt) {
        char* l = ldsB + bb * 32768 + h * 16384 + wave * 1024;
        const bf16* g = pB + (long)(h * 128) * ldb + kt * 64;
        async16(l, g);
        async16(l + 8192, g + (long)64 * ldb);
    };

    const int nk = K >> 6;

    // prologue: tile0 (8 loads) + A of tile1 (4 loads); vmcnt(4) -> tile0 resident
    stgA(0, 0, 0); stgA(0, 1, 0);
    stgB(0, 0, 0); stgB(0, 1, 0);
    stgA(1, 0, 1); stgA(1, 1, 1);
    asm volatile("s_waitcnt vmcnt(4)" ::: "memory");
    BAR;

    f32x4 acc[8][4] = {};
    bf16x8 af03[4][2], af47[4][2], bf01[2][2], bf23[2][2];

    {   // G1(0): af03 + bf01 from buffer 0
        const char* aH = ldsA + hw * 16384;
        const char* bH = ldsB + hbB * 16384 + rrB * 128;
        #pragma unroll
        for (int mf = 0; mf < 4; ++mf) {
            af03[mf][0] = RD8(aH + mf * 2048 + lane2_0);
            af03[mf][1] = RD8(aH + mf * 2048 + lane2_1);
        }
        #pragma unroll
        for (int nf = 0; nf < 2; ++nf) {
            bf01[nf][0] = RD8(bH + nf * 2048 + lane2_0);
            bf01[nf][1] = RD8(bH + nf * 2048 + lane2_1);
        }
    }

    for (int t = 0; t < nk; ++t) {
        const int cur = t & 1;
        const char* aH  = ldsA + cur * 32768 + hw * 16384;
        const char* bH  = ldsB + cur * 32768 + hbB * 16384 + rrB * 128;
        const char* aHn = ldsA + (cur ^ 1) * 32768 + hw * 16384;
        const char* bHn = ldsB + (cur ^ 1) * 32768 + hbB * 16384 + rrB * 128;

        // ---- P1: issue G2 (bf23) || stage B0(t+1); MFMA(af03,bf01) after lgkm(4) ----
        #pragma unroll
        for (int nf = 0; nf < 2; ++nf) {
            bf23[nf][0] = RD8(bH + (nf + 2) * 2048 + lane2_0);
            bf23[nf][1] = RD8(bH + (nf + 2) * 2048 + lane2_1);
        }
        if (t + 1 < nk) stgB(cur ^ 1, 0, t + 1);
        LGKMC(4);                       // G1 complete; G2 (4) still flying under MFMA
        __builtin_amdgcn_s_setprio(1);
        MFMA_Q(af03, 0, bf01, 0);
        __builtin_amdgcn_s_setprio(0);
        BAR;

        // ---- P2: issue G3 (af47) || stage B1(t+1); MFMA(af03,bf23) after lgkm(8) ----
        #pragma unroll
        for (int mf = 0; mf < 4; ++mf) {
            af47[mf][0] = RD8(aH + (mf + 4) * 2048 + lane2_0);
            af47[mf][1] = RD8(aH + (mf + 4) * 2048 + lane2_1);
        }
        if (t + 1 < nk) stgB(cur ^ 1, 1, t + 1);
        LGKMC(8);                       // G2 complete; G3 (8) flying under MFMA
        __builtin_amdgcn_s_setprio(1);
        MFMA_Q(af03, 0, bf23, 2);       // af03 dead after this
        __builtin_amdgcn_s_setprio(0);
        BAR;

        // ---- P3: MFMA(af47,bf01) after lgkm(0) ----
        LGKMC(0);                       // G3 complete
        __builtin_amdgcn_s_setprio(1);
        MFMA_Q(af47, 4, bf01, 0);       // bf01 dead after this
        __builtin_amdgcn_s_setprio(0);
        BAR;

        // ---- P4: stage A(t+2); counted vmcnt; residency barrier; issue G1(t+1);
        //          MFMA(af47,bf23) with NO lgkm wait (reads fly under it) ----
        if (t + 2 < nk) {
            stgA(cur, 0, t + 2);        // A region of cur: all af reads done (P3 barrier)
            stgA(cur, 1, t + 2);
            asm volatile("s_waitcnt vmcnt(4)" ::: "memory");  // tile t+1 resident
        } else {
            asm volatile("s_waitcnt vmcnt(0)" ::: "memory");
        }
        BAR;                            // publish: all waves' slices landed
        if (t + 1 < nk) {
            #pragma unroll
            for (int mf = 0; mf < 4; ++mf) {
                af03[mf][0] = RD8(aHn + mf * 2048 + lane2_0);
                af03[mf][1] = RD8(aHn + mf * 2048 + lane2_1);
            }
            #pragma unroll
            for (int nf = 0; nf < 2; ++nf) {
                bf01[nf][0] = RD8(bHn + nf * 2048 + lane2_0);
                bf01[nf][1] = RD8(bHn + nf * 2048 + lane2_1);
            }
        }
        __builtin_amdgcn_s_setprio(1);
        MFMA_Q(af47, 4, bf23, 2);
        __builtin_amdgcn_s_setprio(0);
        BAR;
    }

    C += (long)b * sC;

    #pragma unroll
    for (int nf = 0; nf < 4; ++nf) {
        const int col = n0 + wq * 64 + nf * 16 + l16;
        float fr = 0.f;
        if (EPI == EPI_SINUS)
            fr = __expf((float)(-(col & ~1)) * (9.210340371976184f / 1024.f)); // exp(-(2i)ln(1e4)/d)
        #pragma unroll
        for (int mf = 0; mf < 8; ++mf) {
            #pragma unroll
            for (int r = 0; r < 4; ++r) {
                const int row = m0 + hw * 128 + mf * 16 + quad * 4 + r; // C/D: row=quad*4+reg, col=l16
                float v = acc[mf][nf][r];
                if (EPI == EPI_SINUS) {
                    float ang = (float)row * fr;
                    // __sinf/__cosf: inline v_sin/v_cos, no libcall (libcall ABI clamped VGPRs)
                    v += (col & 1) ? __cosf(ang) : __sinf(ang);
                }
                if (EPI == EPI_BIAS) v += bias[row];
                if (row < mLimit)
                    C[(long)row * ldc + col] = (CT)v;
            }
        }
    }

    if (EPI == EPI_ATTN) {
        // per-column (max, sum-exp) over this block's 256 rows (rows >= mLimit masked)
        float nmx[4], nsm[4];
        #pragma unroll
        for (int nf = 0; nf < 4; ++nf) {
            float mx = -1e30f;
            #pragma unroll
            for (int mf = 0; mf < 8; ++mf)
                #pragma unroll
                for (int r = 0; r < 4; ++r) {
                    const int row = m0 + hw * 128 + mf * 16 + quad * 4 + r;
                    float v = (row < mLimit) ? acc[mf][nf][r] : -1e30f;
                    mx = fmaxf(mx, v);
                }
            float sm = 0.f;
            #pragma unroll
            for (int mf = 0; mf < 8; ++mf)
                #pragma unroll
                for (int r = 0; r < 4; ++r) {
                    const int row = m0 + hw * 128 + mf * 16 + quad * 4 + r;
                    float v = (row < mLimit) ? acc[mf][nf][r] : -1e30f;
                    sm += __expf(v - mx);   // masked v underflows to 0
                }
            float omx = __shfl_xor(mx, 16), osm = __shfl_xor(sm, 16);
            onl_merge(mx, sm, omx, osm);
            omx = __shfl_xor(mx, 32); osm = __shfl_xor(sm, 32);
            onl_merge(mx, sm, omx, osm);
            nmx[nf] = mx; nsm[nf] = sm;
        }
        float smx = quad == 0 ? nmx[0] : quad == 1 ? nmx[1] : quad == 2 ? nmx[2] : nmx[3];
        float ssm = quad == 0 ? nsm[0] : quad == 1 ? nsm[1] : quad == 2 ? nsm[2] : nsm[3];
        float2* red = (float2*)smem;     // staging LDS dead (final vmcnt(0)+BAR in loop)
        red[wave * 64 + lane] = make_float2(smx, ssm);
        __syncthreads();
        if (wave < 4) {
            float2 x = red[wave * 64 + lane];
            float2 y = red[(wave + 4) * 64 + lane];
            onl_merge(x.x, x.y, y.x, y.y);
            const int col = n0 + wq * 64 + lane;
            const int mt  = m0 >> 8;
            pmx [((long)b * 4 + mt) * 1024 + col] = x.x;
            psum[((long)b * 4 + mt) * 1024 + col] = x.y;
        }
    }
}

// ---------------- small 128x128 2-phase NT GEMM (for tiny weight-fold gemms) ----------------
constexpr int BM = 128, BN = 128, BK = 32;
template <int EPI, typename CT>
__launch_bounds__(256)
__global__ void gemm_nt(const bf16* __restrict__ A, long sA, int lda,
                        const bf16* __restrict__ B, long sB, int ldb,
                        CT* __restrict__ C, long sC, int ldc,
                        int K, int mLimit,
                        const float* __restrict__ bias)
{
    __shared__ __align__(16) bf16 As[BM * BK];
    __shared__ __align__(16) bf16 Bs[BN * BK];

    const int tid  = threadIdx.x;
    const int wave = tid >> 6;
    const int lane = tid & 63;
    const int quad = lane >> 4;
    const int l16  = lane & 15;
    const int b    = blockIdx.z;
    const int m0   = blockIdx.y * BM;
    const int n0   = blockIdx.x * BN;

    A += (long)b * sA;
    B += (long)b * sB;

    const int srow = lane >> 2;
    const int scol = (lane & 3) * 8;
    const bf16* gA = A + (long)(m0 + wave * 32 + srow) * lda + scol;
    const bf16* gB = B + (long)(n0 + wave * 32 + srow) * ldb + scol;
    char* lA = (char*)As + wave * 2048;
    char* lB = (char*)Bs + wave * 2048;

    const int wm = (wave >> 1) * 64;
    const int wn = (wave & 1) * 64;

    f32x4 acc[4][4] = {};

    for (int k0 = 0; k0 < K; k0 += BK) {
        __syncthreads();
        async16(lA,        gA);
        async16(lA + 1024, gA + (long)16 * lda);
        async16(lB,        gB);
        async16(lB + 1024, gB + (long)16 * ldb);
        gA += BK; gB += BK;
        __syncthreads();

        bf16x8 af[4], bfr[4];
        #pragma unroll
        for (int i = 0; i < 4; i++) {
            af[i]  = *(const bf16x8*)(As + (wm + i * 16 + l16) * BK + quad * 8);
            bfr[i] = *(const bf16x8*)(Bs + (wn + i * 16 + l16) * BK + quad * 8);
        }
        #pragma unroll
        for (int mi = 0; mi < 4; mi++)
            #pragma unroll
            for (int ni = 0; ni < 4; ni++)
                acc[mi][ni] = __builtin_amdgcn_mfma_f32_16x16x32_bf16(
                    af[mi], bfr[ni], acc[mi][ni], 0, 0, 0);
    }

    C += (long)b * sC;

    #pragma unroll
    for (int ni = 0; ni < 4; ni++) {
        const int col = n0 + wn + ni * 16 + l16;
        #pragma unroll
        for (int mi = 0; mi < 4; mi++) {
            #pragma unroll
            for (int r = 0; r < 4; r++) {
                const int row = m0 + wm + mi * 16 + quad * 4 + r;
                float v = acc[mi][ni][r];
                if (EPI == EPI_BIAS) v += bias[row];
                if (row < mLimit)
                    C[(long)row * ldc + col] = (CT)v;
            }
        }
    }
}

// f32 -> bf16 flat convert (n % 4 == 0)
__launch_bounds__(256)
__global__ void cvt_f32_bf16(const float* __restrict__ in, bf16* __restrict__ out, int n)
{
    int i = (blockIdx.x * 256 + threadIdx.x) * 4;
    if (i < n) {
        float4 v = *(const float4*)(in + i);
        out[i]     = (bf16)v.x;
        out[i + 1] = (bf16)v.y;
        out[i + 2] = (bf16)v.z;
        out[i + 3] = (bf16)v.w;
    }
}

// batched transpose + f32->bf16: in (rows x cols) f32 -> out (cols x rows) bf16
__launch_bounds__(256)
__global__ void transpose_f32_bf16(const float* __restrict__ in, bf16* __restrict__ out,
                                   int rows, int cols)
{
    __shared__ float tile[32][33];
    const long bs = (long)rows * cols;
    in  += (long)blockIdx.z * bs;
    out += (long)blockIdx.z * bs;
    const int c0 = blockIdx.x * 32, r0 = blockIdx.y * 32;
    const int tx = threadIdx.x, ty = threadIdx.y;
    #pragma unroll
    for (int i = ty; i < 32; i += 8)
        tile[i][tx] = in[(long)(r0 + i) * cols + c0 + tx];
    __syncthreads();
    #pragma unroll
    for (int i = ty; i < 32; i += 8)
        out[(long)(c0 + i) * rows + r0 + tx] = (bf16)tile[tx][i];
}

// batched bf16 transpose: in (rows x cols) -> out (cols x rows)
__launch_bounds__(256)
__global__ void transpose_bf16(const bf16* __restrict__ in, bf16* __restrict__ out,
                               int rows, int cols)
{
    __shared__ bf16 tile[32][33];
    const long bs = (long)rows * cols;
    in  += (long)blockIdx.z * bs;
    out += (long)blockIdx.z * bs;
    const int c0 = blockIdx.x * 32, r0 = blockIdx.y * 32;
    const int tx = threadIdx.x, ty = threadIdx.y;
    #pragma unroll
    for (int i = ty; i < 32; i += 8)
        tile[i][tx] = in[(long)(r0 + i) * cols + c0 + tx];
    __syncthreads();
    #pragma unroll
    for (int i = ty; i < 32; i += 8)
        out[(long)(c0 + i) * rows + r0 + tx] = tile[tx][i];
}

// ---------- softmax normalize + transpose ----------
// Merges the 4 per-mtile partials, normalizes attn columns, writes softT[t][m] directly.
__launch_bounds__(256)
__global__ void softmax_norm_T(const float* __restrict__ attn,
                               const float* __restrict__ pmx,
                               const float* __restrict__ psum,
                               bf16* __restrict__ softT)
{
    __shared__ bf16 tile[64][66];
    const int b  = blockIdx.z;
    const int mt = blockIdx.x;
    const int ct = blockIdx.y;
    const int tx = threadIdx.x & 63;
    const int ty = threadIdx.x >> 6;
    const int col = ct * 64 + tx;

    float MX = -1e30f, SM = 0.f;
    #pragma unroll
    for (int p = 0; p < 4; ++p) {
        float omx = pmx [((long)b * 4 + p) * 1024 + col];
        float osm = psum[((long)b * 4 + p) * 1024 + col];
        onl_merge(MX, SM, omx, osm);
    }
    const float INV = 1.f / SM;

    const float* a = attn + (long)b * (1023l * 1024);
    const int m0 = mt * 64;
    #pragma unroll
    for (int i = ty; i < 64; i += 4) {
        const int m = m0 + i;
        float p = 0.f;
        if (m < 1023) p = __expf(a[(long)m * 1024 + col] - MX) * INV;
        tile[tx][i] = (bf16)p;
    }
    __syncthreads();
    bf16* o = softT + (long)b * (1024l * 1024) + (long)(ct * 64) * 1024 + m0;
    #pragma unroll
    for (int j = ty; j < 64; j += 4)
        o[(long)j * 1024 + tx] = tile[j][tx];
}

extern "C" void kernel_launch(void* const* d_in, const int* in_sizes, int n_in,
                              void* d_out, int out_size, void* d_ws, size_t ws_size,
                              hipStream_t stream)
{
    const float* xs    = (const float*)d_in[0];  // (32,512,1024) f32
    const float* W_emb = (const float*)d_in[1];  // (1024,512)
    const float* W_KQ  = (const float*)d_in[2];  // (1024,1024)
    const float* W_PV  = (const float*)d_in[3];  // (1024,1024)
    const float* W_un  = (const float*)d_in[4];  // (512,1024)
    const float* b_un  = (const float*)d_in[5];  // (512,)

    float* out  = (float*)d_out;                   // (32,512,1024) f32
    float* attn = out + (size_t)32 * 512 * 1024;   // (32,1023,1024) f32

    const long MB = 1024l * 1024;

    // workspace layout (bytes), bf16 buffers
    char* ws = (char*)d_ws;
    const size_t oXsT  = 0;                        // 32*1024*512*2 = 33.5 MB
    const size_t oET   = oXsT + (size_t)33554432;  // 64 MB each below
    const size_t oEn   = oET  + (size_t)67108864;
    const size_t oQT   = oEn  + (size_t)67108864;
    const size_t oR    = oQT  + (size_t)67108864;
    const size_t oWe   = oR   + (size_t)67108864;  // weights bf16
    const size_t oWkq  = oWe  + (size_t)1048576;
    const size_t oWpvT = oWkq + (size_t)2097152;   // W_PV^T bf16 (2 MB)
    const size_t oWun  = oWpvT + (size_t)2097152;
    const size_t oWc   = oWun + (size_t)1048576;   // Wc = Wun@Wpv bf16 (512x1024, 1 MB)
    const size_t need  = oWc  + (size_t)1048576;
    if (ws_size < need) { fprintf(stderr, "ws too small: %zu < %zu\n", ws_size, need); return; }

    bf16* xsT   = (bf16*)(ws + oXsT);
    bf16* ET    = (bf16*)(ws + oET);
    bf16* En    = (bf16*)(ws + oEn);
    bf16* QT    = (bf16*)(ws + oQT);
    bf16* We    = (bf16*)(ws + oWe);
    bf16* Wkq   = (bf16*)(ws + oWkq);
    bf16* WpvT  = (bf16*)(ws + oWpvT);
    bf16* Wun   = (bf16*)(ws + oWun);
    bf16* Wc    = (bf16*)(ws + oWc);
    bf16* softT = QT;                 // reuse: QT dead after attn gemm
    bf16* A1T   = (bf16*)(ws + oR);

    // softmax partials parked in R's space (A1T written only after softmax_norm_T consumed them)
    float* pmx  = (float*)(ws + oR);               // 32*4*1024 f32 = 512 KB
    float* psum = pmx + (size_t)32 * 4 * 1024;     // +512 KB

    const dim3 tb(32, 8);
    const int BIG = 1 << 30;

    // weight converts f32 -> bf16
    cvt_f32_bf16<<<512, 256, 0, stream>>>(W_emb, We, 524288);
    cvt_f32_bf16<<<1024, 256, 0, stream>>>(W_KQ, Wkq, 1048576);
    cvt_f32_bf16<<<512, 256, 0, stream>>>(W_un, Wun, 524288);
    // W_PV (1024x1024 f32) -> WpvT bf16 [e][d]
    transpose_f32_bf16<<<dim3(32, 32, 1), tb, 0, stream>>>(W_PV, WpvT, 1024, 1024);
    // Wc[o][e] = sum_d Wun[o][d] * WpvT[e][d]  (batch-independent fold of W_un @ W_PV)
    gemm_nt<EPI_NONE, bf16><<<dim3(8, 4, 1), 256, 0, stream>>>(
        Wun, 0, 1024, WpvT, 0, 1024, Wc, 0, 1024, 1024, BIG, nullptr);
    // xs (512x1024 f32) -> xsT (1024x512 bf16), per batch
    transpose_f32_bf16<<<dim3(32, 16, 32), tb, 0, stream>>>(xs, xsT, 512, 1024);
    // E^T[t][d] = sum_n xsT[t][n] * We[d][n] + sinusoid(t,d)
    gemm8<EPI_SINUS, bf16><<<dim3(512), 512, 0, stream>>>(
        xsT, 512l * 1024, 512, We, 0, 512, ET, MB, 1024, 512, BIG, nullptr, nullptr, nullptr, 4, 4);
    // E^T -> E (natural [e][m])
    transpose_bf16<<<dim3(32, 32, 32), tb, 0, stream>>>(ET, En, 1024, 1024);
    // Q^T[t][d] = sum_e E^T[t][e] * Wkq[d][e]
    gemm8<EPI_NONE, bf16><<<dim3(512), 512, 0, stream>>>(
        ET, MB, 1024, Wkq, 0, 1024, QT, MB, 1024, 1024, BIG, nullptr, nullptr, nullptr, 4, 4);
    // attn[m][t] = sum_e E^T[m][e] * Q^T[t][e], rows m<1023, f32 -> d_out; + column partials
    gemm8<EPI_ATTN, float><<<dim3(512), 512, 0, stream>>>(
        ET, MB, 1024, QT, MB, 1024, attn, 1023l * 1024, 1024, 1024, 1023, nullptr, pmx, psum, 4, 4);
    // merge partials + normalize + transpose-write softT [t][m] (row 1023 of soft -> 0)
    softmax_norm_T<<<dim3(16, 16, 32), 256, 0, stream>>>(attn, pmx, psum, softT);
    // A1^T[t][e] = S1^T = sum_m softT[t][m] * E[e][m]
    gemm8<EPI_NONE, bf16><<<dim3(512), 512, 0, stream>>>(
        softT, MB, 1024, En, MB, 1024, A1T, MB, 1024, 1024, BIG, nullptr, nullptr, nullptr, 4, 4);
    // out[o][t] = sum_e Wc[o][e] * A1T[t][e] + b_un[o], f32 -> d_out  (PV gemm folded away)
    gemm8<EPI_BIAS, float><<<dim3(256), 512, 0, stream>>>(
        Wc, 0, 1024, A1T, MB, 1024, out, 512l * 1024, 1024, 1024, BIG, b_un, nullptr, nullptr, 2, 4);
}